// Round 1
// baseline (270.846 us; speedup 1.0000x reference)
//
#include <hip/hip_runtime.h>
#include <stdint.h>

// LorentzLinear fused: y = x @ W^T + b ; time = sigmoid(y0)*e^scale + 1.1 ;
// out = [time, y_narrow * sqrt((time^2-1)/max(sum(y_narrow^2),1e-8))]
// M=65536, K=512, N=512. bf16 MFMA GEMM, full-N blocks (BM=64 x BN=512),
// fused row-reduction epilogue. Memory-bound target ~43us.

typedef short short8 __attribute__((ext_vector_type(8)));
typedef unsigned short ushort8 __attribute__((ext_vector_type(8)));
typedef unsigned short ushort4v __attribute__((ext_vector_type(4)));
typedef float f32x4 __attribute__((ext_vector_type(4)));

#define THREADS 512
#define BM 64
#define KTILES 8          // 512 / 64
#define LDS_W(buf) ((buf) * 65536)            // 2 x 64KB  (512 rows x 128B)
#define LDS_X(buf) (131072 + (buf) * 8192)    // 2 x 8KB   (64 rows x 128B)
// total LDS = 147456 B (1 block/CU, 8 waves = 2/SIMD)

__device__ __forceinline__ unsigned short f2bf(float f) {
  union { float f; uint32_t u; } v; v.f = f;
  uint32_t u = v.u;
  return (unsigned short)((u + 0x7FFFu + ((u >> 16) & 1u)) >> 16);  // RNE
}

__device__ __forceinline__ void gload_lds16(const void* g, void* l) {
  __builtin_amdgcn_global_load_lds(
      (const __attribute__((address_space(1))) void*)g,
      (__attribute__((address_space(3))) void*)l, 16, 0, 0);
}

// W fp32 -> bf16 once per launch (d_ws re-poisoned every run)
__global__ void wconv_kernel(const float* __restrict__ w,
                             unsigned short* __restrict__ wb) {
  const int i = (blockIdx.x * blockDim.x + threadIdx.x) * 4;
  float4 f = *(const float4*)(w + i);
  ushort4v h;
  h[0] = f2bf(f.x); h[1] = f2bf(f.y); h[2] = f2bf(f.z); h[3] = f2bf(f.w);
  *(ushort4v*)(wb + i) = h;
}

__global__ __launch_bounds__(THREADS, 2) void lorentz_kernel(
    const float* __restrict__ xg, const unsigned short* __restrict__ wb,
    const float* __restrict__ bg, const float* __restrict__ sg,
    float* __restrict__ out) {
  __shared__ __align__(16) char smem[147456];
  const int t = threadIdx.x;
  const int lane = t & 63;
  const int wid = t >> 6;
  const int wm = wid >> 2;        // 0..1  (m half: 32 rows)
  const int wn = wid & 3;         // 0..3  (n quarter: 128 cols)
  const int l15 = lane & 15;
  const int q = lane >> 4;
  const int bm = blockIdx.x * BM;

  // --- staging address precompute ---
  // W: LDS row = i*64 + (t>>3); swizzled element offset within 64-wide k-tile
  const int wrow0 = t >> 3;                                // 0..63
  const int wswz = ((t & 7) ^ (wrow0 & 7)) << 3;           // elements
  const unsigned short* wsrc0 = wb + wrow0 * 512 + wswz;
  // x: thread loads 8 fp32 of row xm at k-offset xkq
  const int xm = t >> 3;
  const int xkq = (t & 7) << 3;
  const float* xsrc0 = xg + (bm + xm) * 512 + xkq;
  const int xdst_off = xm * 128 + ((xkq << 1) ^ ((xm & 7) << 4));

  f32x4 acc[2][8];
  #pragma unroll
  for (int a = 0; a < 2; ++a)
    #pragma unroll
    for (int n = 0; n < 8; ++n)
      acc[a][n] = (f32x4){0.f, 0.f, 0.f, 0.f};

  auto stage = [&](int buf, int kt) {
    // x reg-loads FIRST (so the convert's vmcnt wait doesn't require the
    // 8 W global_load_lds below to drain)
    const float* xs = xsrc0 + kt * 64;
    float4 f0 = *(const float4*)xs;
    float4 f1 = *(const float4*)(xs + 4);
    // W tile: 512 rows x 64 k bf16, swizzled source -> linear LDS dest
    const unsigned short* ws = wsrc0 + kt * 64;
    char* wd = smem + LDS_W(buf) + t * 16;
    #pragma unroll
    for (int i = 0; i < 8; ++i)
      gload_lds16(ws + i * 32768, wd + i * 8192);
    // convert + swizzled ds_write_b128
    ushort8 h;
    h[0] = f2bf(f0.x); h[1] = f2bf(f0.y); h[2] = f2bf(f0.z); h[3] = f2bf(f0.w);
    h[4] = f2bf(f1.x); h[5] = f2bf(f1.y); h[6] = f2bf(f1.z); h[7] = f2bf(f1.w);
    *(ushort8*)(smem + LDS_X(buf) + xdst_off) = h;
  };

  auto compute = [&](int buf) {
    const char* wsrc = smem + LDS_W(buf);
    const char* xsrc = smem + LDS_X(buf);
    #pragma unroll
    for (int ks = 0; ks < 2; ++ks) {
      const int kb = ks * 64 + q * 16;   // byte offset of this lane's 8 bf16
      short8 af[2];
      #pragma unroll
      for (int mr = 0; mr < 2; ++mr) {
        const int row = wm * 32 + mr * 16 + l15;
        af[mr] = *(const short8*)(xsrc + row * 128 + (kb ^ ((row & 7) << 4)));
      }
      #pragma unroll
      for (int nr = 0; nr < 8; ++nr) {
        const int row = wn * 128 + nr * 16 + l15;
        const short8 bf =
            *(const short8*)(wsrc + row * 128 + (kb ^ ((row & 7) << 4)));
        acc[0][nr] = __builtin_amdgcn_mfma_f32_16x16x32_bf16(af[0], bf,
                                                             acc[0][nr], 0, 0, 0);
        acc[1][nr] = __builtin_amdgcn_mfma_f32_16x16x32_bf16(af[1], bf,
                                                             acc[1][nr], 0, 0, 0);
      }
    }
  };

  stage(0, 0);
  __syncthreads();
  #pragma unroll
  for (int kt = 0; kt < KTILES; ++kt) {
    const int cur = kt & 1;
    if (kt + 1 < KTILES) stage(cur ^ 1, kt + 1);
    compute(cur);
    __syncthreads();
  }

  // ---------------- epilogue ----------------
  const float esc = __expf(sg[0]);
  float* red = (float*)smem;      // reuse W0 region (dead after last barrier)
  float* tsh = red + 64;
  if (t < 64) red[t] = 0.f;

  // bias
  float bv[8];
  #pragma unroll
  for (int nr = 0; nr < 8; ++nr) bv[nr] = bg[wn * 128 + nr * 16 + l15];
  #pragma unroll
  for (int mr = 0; mr < 2; ++mr)
    #pragma unroll
    for (int nr = 0; nr < 8; ++nr)
      #pragma unroll
      for (int j = 0; j < 4; ++j)
        acc[mr][nr][j] += bv[nr];

  const bool col0 = (wn == 0) && (l15 == 0);   // this lane's nr==0 col is global col 0
  float ps[2][4];
  #pragma unroll
  for (int mr = 0; mr < 2; ++mr)
    #pragma unroll
    for (int j = 0; j < 4; ++j) {
      float s = 0.f;
      #pragma unroll
      for (int nr = 0; nr < 8; ++nr) { const float v = acc[mr][nr][j]; s += v * v; }
      if (col0) { const float v = acc[mr][0][j]; s -= v * v; }  // exclude y0
      ps[mr][j] = s;
    }
  #pragma unroll
  for (int msk = 1; msk < 16; msk <<= 1)
    #pragma unroll
    for (int mr = 0; mr < 2; ++mr)
      #pragma unroll
      for (int j = 0; j < 4; ++j)
        ps[mr][j] += __shfl_xor(ps[mr][j], msk, 64);

  __syncthreads();   // red[] zeroed + LDS reuse safe
  if (l15 == 0) {
    #pragma unroll
    for (int mr = 0; mr < 2; ++mr)
      #pragma unroll
      for (int j = 0; j < 4; ++j)
        atomicAdd(&red[wm * 32 + mr * 16 + q * 4 + j], ps[mr][j]);
  }
  if (col0) {
    #pragma unroll
    for (int mr = 0; mr < 2; ++mr)
      #pragma unroll
      for (int j = 0; j < 4; ++j) {
        const float y0 = acc[mr][0][j];
        const float sgm = 1.f / (1.f + __expf(-y0));
        tsh[wm * 32 + mr * 16 + q * 4 + j] = sgm * esc + 1.1f;
      }
  }
  __syncthreads();

  #pragma unroll
  for (int mr = 0; mr < 2; ++mr)
    #pragma unroll
    for (int j = 0; j < 4; ++j) {
      const int r = wm * 32 + mr * 16 + q * 4 + j;
      float denom = red[r];
      denom = denom < 1e-8f ? 1e-8f : denom;
      const float tt = tsh[r];
      const float coef = sqrtf((tt * tt - 1.f) / denom);
      float* orow = out + (size_t)(bm + r) * 512;
      #pragma unroll
      for (int nr = 0; nr < 8; ++nr) {
        const int c = wn * 128 + nr * 16 + l15;
        orow[c] = (c == 0) ? tt : acc[mr][nr][j] * coef;
      }
    }
}

extern "C" void kernel_launch(void* const* d_in, const int* in_sizes, int n_in,
                              void* d_out, int out_size, void* d_ws, size_t ws_size,
                              hipStream_t stream) {
  const float* x = (const float*)d_in[0];
  const float* W = (const float*)d_in[1];
  const float* b = (const float*)d_in[2];
  const float* sc = (const float*)d_in[3];
  float* outp = (float*)d_out;
  unsigned short* wb = (unsigned short*)d_ws;   // 512*512*2 = 512KB scratch

  wconv_kernel<<<256, 256, 0, stream>>>(W, wb);
  lorentz_kernel<<<65536 / BM, THREADS, 0, stream>>>(x, wb, b, sc, outp);
}

// Round 2
// 259.434 us; speedup vs baseline: 1.0440x; 1.0440x over previous
//
#include <hip/hip_runtime.h>
#include <stdint.h>

// LorentzLinear fused: y = x @ W^T + b ; time = sigmoid(y0)*e^scale + 1.1 ;
// out = [time, y_narrow * sqrt((time^2-1)/max(sum(y_narrow^2),1e-8))]
// M=65536, K=512, N=512. bf16 MFMA, BM=64 x BN=512 (full-N) blocks.
// R1: BK=32 -> 73.7KB LDS -> 2 blocks/CU (was 1) to hide barrier drains.

typedef short short8 __attribute__((ext_vector_type(8)));
typedef unsigned short ushort4v __attribute__((ext_vector_type(4)));
typedef float f32x4 __attribute__((ext_vector_type(4)));

#define THREADS 512
#define BM 64
#define KTILES 16         // 512 / 32
#define LDS_W(buf) ((buf) * 32768)            // 2 x 32KB (512 rows x 64B)
#define LDS_X(buf) (65536 + (buf) * 4096)     // 2 x 4KB  (64 rows x 64B)
// total LDS = 73728 B -> 2 blocks/CU (147456 <= 163840)

__device__ __forceinline__ unsigned short f2bf(float f) {
  union { float f; uint32_t u; } v; v.f = f;
  uint32_t u = v.u;
  return (unsigned short)((u + 0x7FFFu + ((u >> 16) & 1u)) >> 16);  // RNE
}

__device__ __forceinline__ void gload_lds16(const void* g, void* l) {
  __builtin_amdgcn_global_load_lds(
      (const __attribute__((address_space(1))) void*)g,
      (__attribute__((address_space(3))) void*)l, 16, 0, 0);
}

// W fp32 -> bf16 once per launch (d_ws re-poisoned every run)
__global__ void wconv_kernel(const float* __restrict__ w,
                             unsigned short* __restrict__ wb) {
  const int i = (blockIdx.x * blockDim.x + threadIdx.x) * 4;
  float4 f = *(const float4*)(w + i);
  ushort4v h;
  h[0] = f2bf(f.x); h[1] = f2bf(f.y); h[2] = f2bf(f.z); h[3] = f2bf(f.w);
  *(ushort4v*)(wb + i) = h;
}

__global__ __launch_bounds__(THREADS, 4) void lorentz_kernel(
    const float* __restrict__ xg, const unsigned short* __restrict__ wb,
    const float* __restrict__ bg, const float* __restrict__ sg,
    float* __restrict__ out) {
  __shared__ __align__(16) char smem[73728];
  const int t = threadIdx.x;
  const int lane = t & 63;
  const int wid = t >> 6;
  const int wm = wid >> 2;        // 0..1  (m half: 32 rows)
  const int wn = wid & 3;         // 0..3  (n quarter: 128 cols)
  const int l15 = lane & 15;
  const int q = lane >> 4;
  const int bm = blockIdx.x * BM;
  // fragment-read swizzle: rows are 64B; phys = kb ^ ((row>>1)&3)<<4.
  // for rows = base16*16 + l15, (row>>1)&3 == (l15>>1)&3 (base multiple of 16)
  const int swzl = ((l15 >> 1) & 3) << 4;

  // --- staging address precompute ---
  // W tile (per kt): 512 rows x 32 k bf16 = 32KB. gload_lds dest is linear:
  // iter i, thread t -> LDS byte i*8192 + t*16 -> row=i*128+t/4, phys slot t%4.
  // pre-swizzle SOURCE: logical slot = (t%4) ^ ((row>>1)&3)
  const int wrow0 = t >> 2;                          // 0..127
  const int wslog = (t & 3) ^ ((wrow0 >> 1) & 3);
  const unsigned short* wsrc0 = wb + wrow0 * 512 + wslog * 8;
  // x tile: 64 rows x 32 k fp32. thread t: row=t/8, 4 floats at (t%8)*4
  const int xm = t >> 3;
  const int xk4 = (t & 7) << 2;
  const float* xsrc0 = xg + (bm + xm) * 512 + xk4;
  const int xdst_off = xm * 64 + ((xk4 << 1) ^ ((((xm) >> 1) & 3) << 4));

  f32x4 acc[2][8];
  #pragma unroll
  for (int a = 0; a < 2; ++a)
    #pragma unroll
    for (int n = 0; n < 8; ++n)
      acc[a][n] = (f32x4){0.f, 0.f, 0.f, 0.f};

  auto stage = [&](int buf, int kt) {
    // x reg-load FIRST so its vmcnt wait can leave W gload_lds in flight
    const float* xs = xsrc0 + kt * 32;
    float4 f0 = *(const float4*)xs;
    const unsigned short* ws = wsrc0 + kt * 32;
    char* wd = smem + LDS_W(buf) + t * 16;
    #pragma unroll
    for (int i = 0; i < 4; ++i)
      gload_lds16(ws + i * 65536, wd + i * 8192);   // +128 rows per iter
    ushort4v h;
    h[0] = f2bf(f0.x); h[1] = f2bf(f0.y); h[2] = f2bf(f0.z); h[3] = f2bf(f0.w);
    *(ushort4v*)(smem + LDS_X(buf) + xdst_off) = h;
  };

  auto compute = [&](int buf) {
    const char* wsrc = smem + LDS_W(buf);
    const char* xsrc = smem + LDS_X(buf);
    const int kb = q * 16;
    short8 af[2];
    #pragma unroll
    for (int mr = 0; mr < 2; ++mr) {
      const int row = wm * 32 + mr * 16 + l15;
      af[mr] = *(const short8*)(xsrc + row * 64 + (kb ^ swzl));
    }
    #pragma unroll
    for (int nr = 0; nr < 8; ++nr) {
      const int row = wn * 128 + nr * 16 + l15;
      const short8 bf = *(const short8*)(wsrc + row * 64 + (kb ^ swzl));
      acc[0][nr] = __builtin_amdgcn_mfma_f32_16x16x32_bf16(af[0], bf,
                                                           acc[0][nr], 0, 0, 0);
      acc[1][nr] = __builtin_amdgcn_mfma_f32_16x16x32_bf16(af[1], bf,
                                                           acc[1][nr], 0, 0, 0);
    }
  };

  stage(0, 0);
  __syncthreads();
  #pragma unroll
  for (int kt = 0; kt < KTILES; ++kt) {
    const int cur = kt & 1;
    if (kt + 1 < KTILES) stage(cur ^ 1, kt + 1);
    compute(cur);
    __syncthreads();
  }

  // ---------------- epilogue ----------------
  const float esc = __expf(sg[0]);
  float* red = (float*)smem;      // W0 region dead after final barrier
  float* tsh = red + 64;
  if (t < 64) red[t] = 0.f;

  // bias
  float bv[8];
  #pragma unroll
  for (int nr = 0; nr < 8; ++nr) bv[nr] = bg[wn * 128 + nr * 16 + l15];
  #pragma unroll
  for (int mr = 0; mr < 2; ++mr)
    #pragma unroll
    for (int nr = 0; nr < 8; ++nr)
      #pragma unroll
      for (int j = 0; j < 4; ++j)
        acc[mr][nr][j] += bv[nr];

  const bool col0 = (wn == 0) && (l15 == 0);   // lane's nr==0 col is global col 0
  float ps[2][4];
  #pragma unroll
  for (int mr = 0; mr < 2; ++mr)
    #pragma unroll
    for (int j = 0; j < 4; ++j) {
      float s = 0.f;
      #pragma unroll
      for (int nr = 0; nr < 8; ++nr) { const float v = acc[mr][nr][j]; s += v * v; }
      if (col0) { const float v = acc[mr][0][j]; s -= v * v; }  // exclude y0
      ps[mr][j] = s;
    }
  #pragma unroll
  for (int msk = 1; msk < 16; msk <<= 1)
    #pragma unroll
    for (int mr = 0; mr < 2; ++mr)
      #pragma unroll
      for (int j = 0; j < 4; ++j)
        ps[mr][j] += __shfl_xor(ps[mr][j], msk, 64);

  __syncthreads();   // red[] zeroed + LDS reuse safe
  if (l15 == 0) {
    #pragma unroll
    for (int mr = 0; mr < 2; ++mr)
      #pragma unroll
      for (int j = 0; j < 4; ++j)
        atomicAdd(&red[wm * 32 + mr * 16 + q * 4 + j], ps[mr][j]);
  }
  if (col0) {
    #pragma unroll
    for (int mr = 0; mr < 2; ++mr)
      #pragma unroll
      for (int j = 0; j < 4; ++j) {
        const float y0 = acc[mr][0][j];
        const float sgm = 1.f / (1.f + __expf(-y0));
        tsh[wm * 32 + mr * 16 + q * 4 + j] = sgm * esc + 1.1f;
      }
  }
  __syncthreads();

  #pragma unroll
  for (int mr = 0; mr < 2; ++mr)
    #pragma unroll
    for (int j = 0; j < 4; ++j) {
      const int r = wm * 32 + mr * 16 + q * 4 + j;
      float denom = red[r];
      denom = denom < 1e-8f ? 1e-8f : denom;
      const float tt = tsh[r];
      const float coef = sqrtf((tt * tt - 1.f) / denom);
      float* orow = out + (size_t)(bm + r) * 512;
      #pragma unroll
      for (int nr = 0; nr < 8; ++nr) {
        const int c = wn * 128 + nr * 16 + l15;
        orow[c] = (c == 0) ? tt : acc[mr][nr][j] * coef;
      }
    }
}

extern "C" void kernel_launch(void* const* d_in, const int* in_sizes, int n_in,
                              void* d_out, int out_size, void* d_ws, size_t ws_size,
                              hipStream_t stream) {
  const float* x = (const float*)d_in[0];
  const float* W = (const float*)d_in[1];
  const float* b = (const float*)d_in[2];
  const float* sc = (const float*)d_in[3];
  float* outp = (float*)d_out;
  unsigned short* wb = (unsigned short*)d_ws;   // 512*512*2 = 512KB scratch

  wconv_kernel<<<256, 256, 0, stream>>>(W, wb);
  lorentz_kernel<<<65536 / BM, THREADS, 0, stream>>>(x, wb, b, sc, outp);
}